// Round 4
// baseline (13462.531 us; speedup 1.0000x reference)
//
#include <hip/hip_runtime.h>
#include <cmath>

#define BB 128
#define TT 365
#define DD 32
#define HH 512
#define G4H 2048  // 4*HH

// ws layout (floats): buf0 [0,65536) | buf1 [65536,131072) | bar (256 uints)
//                     | cst [131328,+65536) (fallback only)

__device__ __forceinline__ float sigf(float z) { return 1.f / (1.f + __expf(-z)); }

// ---------------------------------------------------------------------------
// Persistent kernel: 256 WGs x 512 threads = 4 batch-blocks (32 b) x 64
// n-blocks (8 h-cols -> 32 gate-cols). W slice (69.6 KB) in LDS all steps.
// Wave w handles zc = w*4..w*4+3; lane: ks=lane&7 (K-split), btile=lane>>3.
// Per-batch-block barrier (64 WGs) with s_sleep-throttled spin; h exchanged
// via agent-scope atomics (L2-bypassing, cross-XCD safe).
// ---------------------------------------------------------------------------
__global__ __launch_bounds__(512, 1)
void lstm_persistent(const float* __restrict__ x,
                     const float* __restrict__ Wx,
                     const float* __restrict__ Wh,
                     const float* __restrict__ bias,
                     float* __restrict__ out,
                     float* __restrict__ hws) {
  __shared__ float Wl[32 * 544];      // 69632 B
  __shared__ float Ash[2][32 * 128];  // 32768 B
  __shared__ float Xs[32 * 32];       // 4096 B
  __shared__ float Zx[32 * 32];       // 4096 B  [zc][b]
  __shared__ float Cs[32 * 8];        // 1024 B  [b][nn]
  __shared__ float BiasS[32];
  // total ~111.7 KB -> 1 WG/CU

  const int tid = threadIdx.x;
  const int ks = tid & 7;            // K-split: lane bits 0..2
  const int btile = (tid >> 3) & 7;  // 4 batches each
  const int wave = tid >> 6;         // 0..7 -> zc group w*4..w*4+3
  const int wg = blockIdx.x;
  const int bb = wg & 3;
  const int nb = wg >> 2;            // 0..63
  const int b0g = bb * 32;
  const int n0 = nb * 8;

  for (int idx = tid; idx < 32 * 544; idx += 512) {
    int zc = idx & 31, k = idx >> 5;
    int col = (zc >> 3) * HH + n0 + (zc & 7);
    Wl[zc * 544 + k] = (k < DD) ? Wx[k * G4H + col] : Wh[(k - DD) * G4H + col];
  }
  if (tid < 32) BiasS[tid] = bias[(tid >> 3) * HH + n0 + (tid & 7)];
  if (tid < 256) Cs[tid] = 0.f;

  float* buf0 = hws;
  float* buf1 = hws + BB * HH;
  unsigned int* bar = (unsigned int*)(hws + 2 * BB * HH) + bb * 64;

  __syncthreads();  // Wl ready; h0=0 and bar=0 from host-side memset

  for (int t = 0; t < TT; ++t) {
    const float* hprev = (t & 1) ? buf1 : buf0;
    float* hnext = (t & 1) ? buf0 : buf1;

    // stage x slice (plain cached loads; input is read-only)
    if (tid < 256) {
      int b_l = tid >> 3, kq = tid & 7;
      float4 v =
          *(const float4*)(x + ((size_t)(b0g + b_l) * TT + t) * DD + kq * 4);
      *(float4*)&Xs[b_l * 32 + kq * 4] = v;
    }
    // prefetch h chunk 0 (agent-scope 64-bit atomic loads)
    unsigned long long pre[4];
#pragma unroll
    for (int r = 0; r < 4; ++r) {
      int fidx = r * 512 + tid;  // 2048 u64 = 32 b x 64
      int b_l = fidx >> 6, kk = fidx & 63;
      pre[r] = __hip_atomic_load(
          (const unsigned long long*)(hprev + (size_t)(b0g + b_l) * HH + kk * 2),
          __ATOMIC_RELAXED, __HIP_MEMORY_SCOPE_AGENT);
    }
#pragma unroll
    for (int r = 0; r < 4; ++r) {
      int fidx = r * 512 + tid;
      int b_l = fidx >> 6, kk = fidx & 63;
      *(unsigned long long*)&Ash[0][b_l * 128 + kk * 2] = pre[r];
    }
    __syncthreads();

    float acc[4][4];
#pragma unroll
    for (int i = 0; i < 4; ++i)
#pragma unroll
      for (int c = 0; c < 4; ++c) acc[i][c] = 0.f;

    auto mac4 = [&](const float* Abase, int rstride, const float* Wbase) {
      float4 a4[4], w4[4];
#pragma unroll
      for (int i = 0; i < 4; ++i)
        a4[i] = *(const float4*)(Abase + (btile * 4 + i) * rstride);
#pragma unroll
      for (int c = 0; c < 4; ++c) w4[c] = *(const float4*)(Wbase + c * 544);
#pragma unroll
      for (int i = 0; i < 4; ++i)
#pragma unroll
        for (int c = 0; c < 4; ++c)
          acc[i][c] += a4[i].x * w4[c].x + a4[i].y * w4[c].y +
                       a4[i].z * w4[c].z + a4[i].w * w4[c].w;
    };

#pragma unroll
    for (int ch = 0; ch < 4; ++ch) {
      if (ch < 3) {
#pragma unroll
        for (int r = 0; r < 4; ++r) {
          int fidx = r * 512 + tid;
          int b_l = fidx >> 6, kk = fidx & 63;
          pre[r] = __hip_atomic_load(
              (const unsigned long long*)(hprev + (size_t)(b0g + b_l) * HH +
                                          (ch + 1) * 128 + kk * 2),
              __ATOMIC_RELAXED, __HIP_MEMORY_SCOPE_AGENT);
        }
      }
      if (ch == 0) mac4(&Xs[ks * 4], 32, &Wl[(wave * 4) * 544 + ks * 4]);
#pragma unroll
      for (int j = 0; j < 4; ++j)
        mac4(&Ash[ch & 1][j * 32 + ks * 4], 128,
             &Wl[(wave * 4) * 544 + DD + ch * 128 + j * 32 + ks * 4]);
      if (ch < 3) {
#pragma unroll
        for (int r = 0; r < 4; ++r) {
          int fidx = r * 512 + tid;
          int b_l = fidx >> 6, kk = fidx & 63;
          *(unsigned long long*)&Ash[(ch + 1) & 1][b_l * 128 + kk * 2] = pre[r];
        }
      }
      __syncthreads();
    }

    // reduce over ks (lane bits 0..2)
#pragma unroll
    for (int i = 0; i < 4; ++i)
#pragma unroll
      for (int c = 0; c < 4; ++c) {
        float v = acc[i][c];
        v += __shfl_xor(v, 1);
        v += __shfl_xor(v, 2);
        v += __shfl_xor(v, 4);
        acc[i][c] = v;
      }

    if (ks == 0) {
#pragma unroll
      for (int c = 0; c < 4; ++c)
#pragma unroll
        for (int i = 0; i < 4; ++i)
          Zx[(wave * 4 + c) * 32 + btile * 4 + i] =
              acc[i][c] + BiasS[wave * 4 + c];
    }
    __syncthreads();

    // gate phase: one thread per batch, all 8 h-cols; vectorized stores
    if (tid < 32) {
      int b_l = tid;
      float hv[8];
#pragma unroll
      for (int nn = 0; nn < 8; ++nn) {
        float zi = Zx[(0 + nn) * 32 + b_l];
        float zf = Zx[(8 + nn) * 32 + b_l];
        float zg = Zx[(16 + nn) * 32 + b_l];
        float zo = Zx[(24 + nn) * 32 + b_l];
        float cnew = sigf(zf) * Cs[b_l * 8 + nn] + sigf(zi) * tanhf(zg);
        Cs[b_l * 8 + nn] = cnew;
        hv[nn] = sigf(zo) * tanhf(cnew);
      }
      int bg = b0g + b_l;
      float* hdst = hnext + (size_t)bg * HH + n0;
#pragma unroll
      for (int j = 0; j < 4; ++j) {
        unsigned long long u;
        __builtin_memcpy(&u, &hv[j * 2], 8);
        __hip_atomic_store((unsigned long long*)(hdst + j * 2), u,
                           __ATOMIC_RELAXED, __HIP_MEMORY_SCOPE_AGENT);
      }
      float* odst = out + ((size_t)bg * TT + t) * HH + n0;
      *(float4*)odst = *(float4*)&hv[0];
      *(float4*)(odst + 4) = *(float4*)&hv[4];
    }
    __syncthreads();  // wave 0 drains vmcnt before arriving

    if (tid == 0) {
      __hip_atomic_fetch_add(bar, 1u, __ATOMIC_RELAXED,
                             __HIP_MEMORY_SCOPE_AGENT);
      unsigned int target = 64u * (unsigned)(t + 1);
      while (__hip_atomic_load(bar, __ATOMIC_RELAXED,
                               __HIP_MEMORY_SCOPE_AGENT) < target) {
        __builtin_amdgcn_s_sleep(8);
      }
    }
    __syncthreads();
  }
}

// ---------------------------------------------------------------------------
// Fallback: one launch per timestep (kernel-boundary coherence). Only used if
// the cooperative launch is rejected.
// ---------------------------------------------------------------------------
__global__ __launch_bounds__(256, 2)
void lstm_step(const float* __restrict__ x, const float* __restrict__ Wx,
               const float* __restrict__ Wh, const float* __restrict__ bias,
               float* __restrict__ out, const float* __restrict__ hprev,
               float* __restrict__ hnext, float* __restrict__ cst, int t) {
  __shared__ float Wl[16 * 544];
  __shared__ float Ash[32 * 128];
  __shared__ float Xs[32 * 32];
  __shared__ float Zx[4][32][4];
  __shared__ float BiasS[16];

  const int tid = threadIdx.x;
  const int ks = tid & 7;
  const int btile = (tid >> 3) & 7;
  const int ctile = tid >> 6;
  const int wg = blockIdx.x;
  const int bb = wg & 3;
  const int nb = wg >> 2;
  const int b0g = bb * 32;
  const int n0 = nb * 4;

  for (int idx = tid; idx < 16 * 544; idx += 256) {
    int zc = idx & 15, k = idx >> 4;
    int col = (zc >> 2) * HH + n0 + (zc & 3);
    Wl[zc * 544 + k] = (k < DD) ? Wx[k * G4H + col] : Wh[(k - DD) * G4H + col];
  }
  if (tid < 16) BiasS[tid] = bias[(tid >> 2) * HH + n0 + (tid & 3)];

  {
    int b_l = tid >> 3, kq = tid & 7;
    float4 v = *(const float4*)(x + ((size_t)(b0g + b_l) * TT + t) * DD + kq * 4);
    *(float4*)&Xs[b_l * 32 + kq * 4] = v;
  }

  float acc[4][4];
#pragma unroll
  for (int i = 0; i < 4; ++i)
#pragma unroll
    for (int c = 0; c < 4; ++c) acc[i][c] = 0.f;

  auto mac4 = [&](const float* Abase, int rstride, const float* Wbase) {
    float4 a4[4], w4[4];
#pragma unroll
    for (int i = 0; i < 4; ++i)
      a4[i] = *(const float4*)(Abase + (btile * 4 + i) * rstride);
#pragma unroll
    for (int c = 0; c < 4; ++c) w4[c] = *(const float4*)(Wbase + c * 544);
#pragma unroll
    for (int i = 0; i < 4; ++i)
#pragma unroll
      for (int c = 0; c < 4; ++c)
        acc[i][c] += a4[i].x * w4[c].x + a4[i].y * w4[c].y +
                     a4[i].z * w4[c].z + a4[i].w * w4[c].w;
  };

  for (int ch = 0; ch < 4; ++ch) {
    __syncthreads();
    for (int r = 0; r < 4; ++r) {
      int fidx = r * 256 + tid;
      int b_l = fidx >> 5, kq = fidx & 31;
      float4 v = *(const float4*)(hprev + (size_t)(b0g + b_l) * HH + ch * 128 +
                                  kq * 4);
      *(float4*)&Ash[b_l * 128 + kq * 4] = v;
    }
    __syncthreads();
    if (ch == 0) mac4(&Xs[ks * 4], 32, &Wl[(ctile * 4) * 544 + ks * 4]);
#pragma unroll
    for (int j = 0; j < 4; ++j)
      mac4(&Ash[j * 32 + ks * 4], 128,
           &Wl[(ctile * 4) * 544 + DD + ch * 128 + j * 32 + ks * 4]);
  }

#pragma unroll
  for (int i = 0; i < 4; ++i)
#pragma unroll
    for (int c = 0; c < 4; ++c) {
      float v = acc[i][c];
      v += __shfl_xor(v, 1);
      v += __shfl_xor(v, 2);
      v += __shfl_xor(v, 4);
      acc[i][c] = v;
    }

  if (ks == 0) {
#pragma unroll
    for (int i = 0; i < 4; ++i)
#pragma unroll
      for (int c = 0; c < 4; ++c)
        Zx[ctile][btile * 4 + i][c] = acc[i][c] + BiasS[ctile * 4 + c];
  }
  __syncthreads();

  if (tid < 128) {
    int b_l = tid >> 2, nn = tid & 3;
    float zi = Zx[0][b_l][nn], zf = Zx[1][b_l][nn];
    float zg = Zx[2][b_l][nn], zo = Zx[3][b_l][nn];
    int bg = b0g + b_l, col = n0 + nn;
    size_t cidx = (size_t)bg * HH + col;
    float cnew = sigf(zf) * cst[cidx] + sigf(zi) * tanhf(zg);
    cst[cidx] = cnew;
    float hv = sigf(zo) * tanhf(cnew);
    hnext[cidx] = hv;
    out[((size_t)bg * TT + t) * HH + col] = hv;
  }
}

extern "C" void kernel_launch(void* const* d_in, const int* in_sizes, int n_in,
                              void* d_out, int out_size, void* d_ws, size_t ws_size,
                              hipStream_t stream) {
  const float* x = (const float*)d_in[0];
  const float* Wx = (const float*)d_in[1];
  const float* Wh = (const float*)d_in[2];
  const float* bv = (const float*)d_in[3];
  float* out = (float*)d_out;
  float* hws = (float*)d_ws;

  // zero: buf0 | buf1 | barrier counters | cst
  hipMemsetAsync(d_ws, 0, (size_t)(3 * 65536 + 256) * 4, stream);

  void* args[] = {(void*)&x, (void*)&Wx, (void*)&Wh,
                  (void*)&bv, (void*)&out, (void*)&hws};
  hipError_t err = hipLaunchCooperativeKernel(
      reinterpret_cast<void*>(lstm_persistent), dim3(256), dim3(512), args, 0,
      stream);
  if (err != hipSuccess) {
    (void)hipGetLastError();
    float* buf0 = hws;
    float* buf1 = hws + BB * HH;
    float* cst = hws + 2 * BB * HH + 256;
    for (int t = 0; t < TT; ++t) {
      const float* hp = (t & 1) ? buf1 : buf0;
      float* hn = (t & 1) ? buf0 : buf1;
      lstm_step<<<dim3(512), dim3(256), 0, stream>>>(x, Wx, Wh, bv, out, hp, hn,
                                                     cst, t);
    }
  }
}